// Round 7
// baseline (288.474 us; speedup 1.0000x reference)
//
#include <hip/hip_runtime.h>
#include <math.h>

#define N_NODES 50000
#define F_IN 256
#define HID 128
#define C_OUT 40
#define BINS ((N_NODES + 255) / 256)   // 196 buckets of 256 nodes

typedef __attribute__((ext_vector_type(8))) short short8;
typedef __attribute__((ext_vector_type(4))) float floatx4;
typedef __attribute__((ext_vector_type(2))) float floatx2;

__device__ __forceinline__ unsigned short f2bf(float f) {
    unsigned int u = __float_as_uint(f);
    unsigned int r = (u + 0x7FFFu + ((u >> 16) & 1u)) >> 16;
    return (unsigned short)r;
}
__device__ __forceinline__ unsigned int pack2bf(float a, float b) {
    return (unsigned int)f2bf(a) | ((unsigned int)f2bf(b) << 16);
}
__device__ __forceinline__ float bf_lo(unsigned int u) { return __uint_as_float(u << 16); }
__device__ __forceinline__ float bf_hi(unsigned int u) { return __uint_as_float(u & 0xFFFF0000u); }

// ------- phase 1 (fused): bucket histogram + castW1 + last-block scan -------
__global__ void k_hist(const int* __restrict__ dst, int E, int* __restrict__ binCount,
                       int* __restrict__ doneCnt,
                       const float* __restrict__ W1, unsigned short* __restrict__ W1bT,
                       int* __restrict__ bucketBase, int* __restrict__ binCursor,
                       int* __restrict__ offsets) {
    __shared__ int h[BINS];
    __shared__ int sd[256];
    __shared__ int lastFlag;
    int t = threadIdx.x, b = blockIdx.x;
    for (int i = t; i < BINS; i += 256) h[i] = 0;
    // side work: cast W1 -> bf16 transposed [HID][F_IN] (blocks 0..127)
    if (b < 128) {
        int i = b * 256 + t;
        int n = i >> 8, k = i & 255;
        W1bT[i] = f2bf(W1[(size_t)k * HID + n]);
    }
    __syncthreads();
    for (int e = b * 256 + t; e < E; e += gridDim.x * 256)
        atomicAdd(&h[dst[e] >> 8], 1);
    __syncthreads();
    for (int i = t; i < BINS; i += 256)
        if (h[i]) atomicAdd(&binCount[i], h[i]);
    __threadfence();
    if (t == 0) lastFlag = (atomicAdd(doneCnt, 1) == (int)gridDim.x - 1);
    __syncthreads();
    if (lastFlag) {
        __threadfence();
        int v = (t < BINS) ? binCount[t] : 0;
        sd[t] = v; __syncthreads();
        for (int off = 1; off < 256; off <<= 1) {
            int tmp = (t >= off) ? sd[t - off] : 0;
            __syncthreads();
            sd[t] += tmp;
            __syncthreads();
        }
        int ex = sd[t] - v;
        if (t < BINS) { bucketBase[t] = ex; binCursor[t] = ex; }
        if (t == 0) { bucketBase[BINS] = E; offsets[N_NODES] = E; }
    }
}

// ---------------- phase 3: partition edges into buckets ----------------
#define PCHUNK 4096
#define PTHREADS 256
__launch_bounds__(PTHREADS)
__global__ void k_partition(const int* __restrict__ src, const int* __restrict__ dst, int E,
                            int* __restrict__ binCursor, unsigned int* __restrict__ packed) {
    __shared__ unsigned int lpack[PCHUNK];   // (local_dst<<16)|src
    __shared__ unsigned int lpos[PCHUNK];    // (rank<<8)|bin
    __shared__ int lcnt[BINS];
    __shared__ int lrun[BINS];
    int t = threadIdx.x;
    int base = blockIdx.x * PCHUNK;
    int n = E - base; if (n > PCHUNK) n = PCHUNK;
    for (int i = t; i < BINS; i += PTHREADS) lcnt[i] = 0;
    __syncthreads();
    for (int i = t; i < n; i += PTHREADS) {
        int d = dst[base + i], s = src[base + i];
        int bin = d >> 8;
        unsigned int r = (unsigned int)atomicAdd(&lcnt[bin], 1);
        lpack[i] = ((unsigned int)(d & 255) << 16) | (unsigned int)s;
        lpos[i] = (r << 8) | (unsigned int)bin;
    }
    __syncthreads();
    if (t < BINS && lcnt[t] > 0) lrun[t] = atomicAdd(&binCursor[t], lcnt[t]);
    __syncthreads();
    for (int i = t; i < n; i += PTHREADS) {
        unsigned int p = lpos[i];
        int bin = p & 255;
        unsigned int r = p >> 8;
        packed[(size_t)lrun[bin] + r] = lpack[i];
    }
}

// ---------------- phase 4: per-bucket CSR (offsets, dinv, col) ----------------
__launch_bounds__(256)
__global__ void k_bucket_csr(const unsigned int* __restrict__ packed, const int* __restrict__ bucketBase,
                             int* __restrict__ offsets, float* __restrict__ dinv,
                             unsigned short* __restrict__ col, int N) {
    __shared__ int lcnt[256];
    __shared__ int lscan[256];
    __shared__ int lofs[256];
    int b = blockIdx.x, t = threadIdx.x;
    int s = bucketBase[b], e = bucketBase[b + 1];
    lcnt[t] = 0;
    __syncthreads();
    for (int i = s + t; i < e; i += 256) atomicAdd(&lcnt[packed[i] >> 16], 1);
    __syncthreads();
    int v = lcnt[t];
    lscan[t] = v;
    __syncthreads();
    for (int off = 1; off < 256; off <<= 1) {
        int tmp = (t >= off) ? lscan[t - off] : 0;
        __syncthreads();
        lscan[t] += tmp;
        __syncthreads();
    }
    int ex = lscan[t] - v;
    int node = b * 256 + t;
    if (node < N) {
        offsets[node] = s + ex;
        dinv[node] = rsqrtf((float)(v + 1));   // deg incl. self-loop
    }
    __syncthreads();
    lofs[t] = ex;
    lcnt[t] = 0;
    __syncthreads();
    for (int i = s + t; i < e; i += 256) {
        unsigned int p = packed[i];
        int ld = (int)(p >> 16);
        int r = atomicAdd(&lcnt[ld], 1);
        col[(size_t)s + lofs[ld] + r] = (unsigned short)(p & 0xFFFFu);
    }
}

// ---------------- GEMM1 (MFMA bf16): y1f = fp8((x @ W1) * dinv[row]) ----------------
__launch_bounds__(256)
__global__ void k_gemm1(const float* __restrict__ A, const unsigned short* __restrict__ BT,
                        const float* __restrict__ dinv, unsigned short* __restrict__ Yf, int M) {
    __shared__ __align__(16) unsigned short As[64][72];    // 64 rows x 64 bf16 (+8 pad)
    __shared__ __align__(16) unsigned short Bs[128][72];   // 128 n-rows x 64 bf16 (+8 pad)
    int t = threadIdx.x;
    int w = t >> 6, lane = t & 63;
    int q = lane >> 4, m = lane & 15;
    int row0 = blockIdx.x * 64;

    floatx4 acc[4][2];
#pragma unroll
    for (int rt = 0; rt < 4; rt++)
#pragma unroll
        for (int ct = 0; ct < 2; ct++) acc[rt][ct] = (floatx4){0.f, 0.f, 0.f, 0.f};

    int ar = t >> 2;
    int ac = (t & 3) * 16;
    int brow = t >> 1;
    int bh = (t & 1) * 32;

    for (int k0 = 0; k0 < F_IN; k0 += 64) {
        {
            int grow = row0 + ar;
            float4 v0, v1, v2, v3;
            if (grow < M) {
                const float* sp = A + (size_t)grow * F_IN + k0 + ac;
                v0 = *(const float4*)(sp);     v1 = *(const float4*)(sp + 4);
                v2 = *(const float4*)(sp + 8); v3 = *(const float4*)(sp + 12);
            } else {
                v0 = v1 = v2 = v3 = make_float4(0.f, 0.f, 0.f, 0.f);
            }
            uint4 u0, u1;
            u0.x = pack2bf(v0.x, v0.y); u0.y = pack2bf(v0.z, v0.w);
            u0.z = pack2bf(v1.x, v1.y); u0.w = pack2bf(v1.z, v1.w);
            u1.x = pack2bf(v2.x, v2.y); u1.y = pack2bf(v2.z, v2.w);
            u1.z = pack2bf(v3.x, v3.y); u1.w = pack2bf(v3.z, v3.w);
            *(uint4*)&As[ar][ac] = u0;
            *(uint4*)&As[ar][ac + 8] = u1;
        }
        {
            const unsigned short* sp = BT + (size_t)brow * F_IN + k0 + bh;
            uint4 b0 = *(const uint4*)(sp);
            uint4 b1 = *(const uint4*)(sp + 8);
            uint4 b2 = *(const uint4*)(sp + 16);
            uint4 b3 = *(const uint4*)(sp + 24);
            *(uint4*)&Bs[brow][bh] = b0;
            *(uint4*)&Bs[brow][bh + 8] = b1;
            *(uint4*)&Bs[brow][bh + 16] = b2;
            *(uint4*)&Bs[brow][bh + 24] = b3;
        }
        __syncthreads();
#pragma unroll
        for (int kc = 0; kc < 64; kc += 32) {
            short8 af[4];
#pragma unroll
            for (int rt = 0; rt < 4; rt++)
                af[rt] = *(const short8*)&As[rt * 16 + m][kc + q * 8];
#pragma unroll
            for (int ct = 0; ct < 2; ct++) {
                short8 bfr = *(const short8*)&Bs[w * 32 + ct * 16 + m][kc + q * 8];
#pragma unroll
                for (int rt = 0; rt < 4; rt++)
                    acc[rt][ct] = __builtin_amdgcn_mfma_f32_16x16x32_bf16(af[rt], bfr, acc[rt][ct], 0, 0, 0);
            }
        }
        __syncthreads();
    }
#pragma unroll
    for (int rt = 0; rt < 4; rt++) {
#pragma unroll
        for (int r = 0; r < 4; r++) {
            int grow = row0 + rt * 16 + q * 4 + r;
            if (grow < M) {
                float d = dinv[grow];
                int pk = __builtin_amdgcn_cvt_pk_fp8_f32(acc[rt][0][r] * d, acc[rt][1][r] * d, 0, false);
                Yf[(size_t)grow * 64 + w * 16 + m] = (unsigned short)pk;
            }
        }
    }
}

// ---------------- GEMM2: y2b = bf16((hid @ W2) * dinv[row]) ----------------
__launch_bounds__(256)
__global__ void k_gemm2(const float* __restrict__ A, const float* __restrict__ B,
                        const float* __restrict__ dinv, unsigned short* __restrict__ Yb, int M) {
    const int BM = 128, BK = 32, TM = 4, TN = 5;
    __shared__ float As[BM][BK + 4];
    __shared__ float Bs[BK][C_OUT];
    int t = threadIdx.x;
    int tx = t & 7;
    int ty = t >> 3;
    int row0 = blockIdx.x * BM;
    float acc[TM][TN];
#pragma unroll
    for (int i = 0; i < TM; i++)
#pragma unroll
        for (int j = 0; j < TN; j++) acc[i][j] = 0.f;

    int am = t >> 1;

    for (int k0 = 0; k0 < HID; k0 += BK) {
#pragma unroll
        for (int h = 0; h < 4; h++) {
            int kq = (t & 1) + h * 2;
            int row = row0 + am;
            float4 v = (row < M) ? *(const float4*)(A + (size_t)row * HID + k0 + kq * 4)
                                 : make_float4(0.f, 0.f, 0.f, 0.f);
            As[am][kq * 4 + 0] = v.x; As[am][kq * 4 + 1] = v.y;
            As[am][kq * 4 + 2] = v.z; As[am][kq * 4 + 3] = v.w;
        }
        for (int l = t; l < BK * (C_OUT / 4); l += 256) {
            int kk = l / (C_OUT / 4), qq = l % (C_OUT / 4);
            *(float4*)&Bs[kk][qq * 4] = *(const float4*)(B + (size_t)(k0 + kk) * C_OUT + qq * 4);
        }
        __syncthreads();
#pragma unroll
        for (int kk = 0; kk < BK; kk++) {
            float a[TM], bv[TN];
#pragma unroll
            for (int i = 0; i < TM; i++) a[i] = As[ty * TM + i][kk];
#pragma unroll
            for (int j = 0; j < TN; j++) bv[j] = Bs[kk][tx * TN + j];
#pragma unroll
            for (int i = 0; i < TM; i++)
#pragma unroll
                for (int j = 0; j < TN; j++) acc[i][j] = fmaf(a[i], bv[j], acc[i][j]);
        }
        __syncthreads();
    }
#pragma unroll
    for (int i = 0; i < TM; i++) {
        int row = row0 + ty * TM + i;
        if (row < M) {
            float d = dinv[row];
#pragma unroll
            for (int j = 0; j < TN; j++)
                Yb[(size_t)row * C_OUT + tx * TN + j] = f2bf(acc[i][j] * d);
        }
    }
}

// ---------------- agg1: 16 lanes/edge (uint2 fp8), 4 edges/pass, 2x unrolled ----------------
__device__ __forceinline__ void fp8acc(uint2 v, float* accLo, float* accHi) {
    floatx2 d0 = __builtin_amdgcn_cvt_pk_f32_fp8(v.x, false);
    floatx2 d1 = __builtin_amdgcn_cvt_pk_f32_fp8(v.x, true);
    floatx2 d2 = __builtin_amdgcn_cvt_pk_f32_fp8(v.y, false);
    floatx2 d3 = __builtin_amdgcn_cvt_pk_f32_fp8(v.y, true);
    accLo[0] += d0[0]; accHi[0] += d0[1];
    accLo[1] += d1[0]; accHi[1] += d1[1];
    accLo[2] += d2[0]; accHi[2] += d2[1];
    accLo[3] += d3[0]; accHi[3] += d3[1];
}

__launch_bounds__(256)
__global__ void k_agg1(const uint2* __restrict__ y1f2, const unsigned short* __restrict__ col,
                       const int* __restrict__ offsets, const float* __restrict__ dinv,
                       const float* __restrict__ b1, float* __restrict__ hid, int N) {
    int lane = threadIdx.x & 63;
    int w = threadIdx.x >> 6;
    int node = blockIdx.x * 4 + w;
    if (node >= N) return;
    int g = lane >> 4;      // edge group 0..3
    int lg = lane & 15;     // 16 lanes x uint2 = 128 B row
    int s = offsets[node], e = offsets[node + 1];

    float accLo[4], accHi[4];
    if (g == 0) {
        fp8acc(y1f2[(size_t)node * 16 + lg],
               (accLo[0] = accLo[1] = accLo[2] = accLo[3] = 0.f, accLo),
               (accHi[0] = accHi[1] = accHi[2] = accHi[3] = 0.f, accHi));
    } else {
#pragma unroll
        for (int i = 0; i < 4; i++) { accLo[i] = 0.f; accHi[i] = 0.f; }
    }

    for (int t0 = s; t0 < e; t0 += 64) {
        int cnt = e - t0; if (cnt > 64) cnt = 64;
        int jreg = (lane < cnt) ? (int)col[t0 + lane] : 0;
        int passes = (cnt + 3) >> 2;
        int p = 0;
        for (; p + 2 <= passes; p += 2) {
            int idx0 = p * 4 + g, idx1 = idx0 + 4;
            bool va = idx0 < cnt, vb = idx1 < cnt;
            int j0 = __shfl(jreg, va ? idx0 : 0);
            int j1 = __shfl(jreg, vb ? idx1 : 0);
            uint2 u0, u1;
            if (va) u0 = y1f2[(size_t)j0 * 16 + lg];
            if (vb) u1 = y1f2[(size_t)j1 * 16 + lg];
            if (va) fp8acc(u0, accLo, accHi);
            if (vb) fp8acc(u1, accLo, accHi);
        }
        for (; p < passes; p++) {
            int idx = p * 4 + g;
            bool valid = idx < cnt;
            int j = __shfl(jreg, valid ? idx : 0);
            if (valid) fp8acc(y1f2[(size_t)j * 16 + lg], accLo, accHi);
        }
    }
#pragma unroll
    for (int i = 0; i < 4; i++) {
        accLo[i] += __shfl(accLo[i], lane + 32);
        accHi[i] += __shfl(accHi[i], lane + 32);
    }
#pragma unroll
    for (int i = 0; i < 4; i++) {
        accLo[i] += __shfl(accLo[i], lane + 16);
        accHi[i] += __shfl(accHi[i], lane + 16);
    }
    if (lane < 16) {
        float d = dinv[node];
        int base = (lg >> 2) * 32 + (lg & 3) * 4;
        float4 bbL = *(const float4*)(b1 + base);
        float4 bbH = *(const float4*)(b1 + base + 16);
        float4 oL, oH;
        oL.x = fmaxf(fmaf(d, accLo[0], bbL.x), 0.f);
        oL.y = fmaxf(fmaf(d, accLo[1], bbL.y), 0.f);
        oL.z = fmaxf(fmaf(d, accLo[2], bbL.z), 0.f);
        oL.w = fmaxf(fmaf(d, accLo[3], bbL.w), 0.f);
        oH.x = fmaxf(fmaf(d, accHi[0], bbH.x), 0.f);
        oH.y = fmaxf(fmaf(d, accHi[1], bbH.y), 0.f);
        oH.z = fmaxf(fmaf(d, accHi[2], bbH.z), 0.f);
        oH.w = fmaxf(fmaf(d, accHi[3], bbH.w), 0.f);
        *(float4*)(hid + (size_t)node * HID + base) = oL;
        *(float4*)(hid + (size_t)node * HID + base + 16) = oH;
    }
}

// ---------------- agg2: 10 lanes/edge (uint2), 6 edges/pass, 2x unrolled + softmax ----------------
__launch_bounds__(256)
__global__ void k_agg2(const uint2* __restrict__ y2b2, const unsigned short* __restrict__ col,
                       const int* __restrict__ offsets, const float* __restrict__ dinv,
                       const float* __restrict__ b2, float* __restrict__ x2out,
                       float* __restrict__ logp, int N) {
    int lane = threadIdx.x & 63;
    int w = threadIdx.x >> 6;
    int node = blockIdx.x * 4 + w;
    if (node >= N) return;
    int g = lane / 10;
    int lg = lane - g * 10;
    bool lact = lane < 60;
    int s = offsets[node], e = offsets[node + 1];

    float a0, a1, a2, a3;
    if (lact && g == 0) {
        uint2 sv = y2b2[(size_t)node * 10 + lg];
        a0 = bf_lo(sv.x); a1 = bf_hi(sv.x); a2 = bf_lo(sv.y); a3 = bf_hi(sv.y);
    } else { a0 = a1 = a2 = a3 = 0.f; }

    for (int t0 = s; t0 < e; t0 += 60) {
        int cnt = e - t0; if (cnt > 60) cnt = 60;
        int jreg = (lane < cnt) ? (int)col[t0 + lane] : 0;
        int passes = (cnt + 5) / 6;
        int p = 0;
        for (; p + 2 <= passes; p += 2) {
            int idx0 = p * 6 + g, idx1 = idx0 + 6;
            bool va = lact && idx0 < cnt, vb = lact && idx1 < cnt;
            int j0 = __shfl(jreg, va ? idx0 : 0);
            int j1 = __shfl(jreg, vb ? idx1 : 0);
            uint2 u0, u1;
            if (va) u0 = y2b2[(size_t)j0 * 10 + lg];
            if (vb) u1 = y2b2[(size_t)j1 * 10 + lg];
            if (va) { a0 += bf_lo(u0.x); a1 += bf_hi(u0.x); a2 += bf_lo(u0.y); a3 += bf_hi(u0.y); }
            if (vb) { a0 += bf_lo(u1.x); a1 += bf_hi(u1.x); a2 += bf_lo(u1.y); a3 += bf_hi(u1.y); }
        }
        for (; p < passes; p++) {
            int idx = p * 6 + g;
            bool valid = lact && idx < cnt;
            int j = __shfl(jreg, valid ? idx : 0);
            if (valid) {
                uint2 v = y2b2[(size_t)j * 10 + lg];
                a0 += bf_lo(v.x); a1 += bf_hi(v.x);
                a2 += bf_lo(v.y); a3 += bf_hi(v.y);
            }
        }
    }
    a0 += __shfl(a0, lane + 30); a1 += __shfl(a1, lane + 30);
    a2 += __shfl(a2, lane + 30); a3 += __shfl(a3, lane + 30);
    float r0 = a0 + __shfl(a0, lane + 10) + __shfl(a0, lane + 20);
    float r1 = a1 + __shfl(a1, lane + 10) + __shfl(a1, lane + 20);
    float r2 = a2 + __shfl(a2, lane + 10) + __shfl(a2, lane + 20);
    float r3 = a3 + __shfl(a3, lane + 10) + __shfl(a3, lane + 20);

    float x0, x1, x2v, x3;
    if (lane < 10) {
        float d = dinv[node];
        float4 bb = ((const float4*)b2)[lg];
        x0 = fmaf(d, r0, bb.x); x1 = fmaf(d, r1, bb.y);
        x2v = fmaf(d, r2, bb.z); x3 = fmaf(d, r3, bb.w);
        float4* xo = (float4*)(x2out + (size_t)node * C_OUT);
        xo[lg] = make_float4(x0, x1, x2v, x3);
    } else { x0 = x1 = x2v = x3 = -INFINITY; }

    float m = fmaxf(fmaxf(x0, x1), fmaxf(x2v, x3));
#pragma unroll
    for (int off = 1; off < 16; off <<= 1) m = fmaxf(m, __shfl_xor(m, off));
    float sum = (lane < 10) ? (expf(x0 - m) + expf(x1 - m) + expf(x2v - m) + expf(x3 - m)) : 0.f;
#pragma unroll
    for (int off = 1; off < 16; off <<= 1) sum += __shfl_xor(sum, off);
    if (lane < 10) {
        float lse = m + logf(sum);
        float4* lo = (float4*)(logp + (size_t)node * C_OUT);
        lo[lg] = make_float4(x0 - lse, x1 - lse, x2v - lse, x3 - lse);
    }
}

// ---------------- launcher ----------------
extern "C" void kernel_launch(void* const* d_in, const int* in_sizes, int n_in,
                              void* d_out, int out_size, void* d_ws, size_t ws_size,
                              hipStream_t stream) {
    const float* x  = (const float*)d_in[0];
    const int*   ei = (const int*)d_in[1];
    const float* W1 = (const float*)d_in[2];
    const float* b1 = (const float*)d_in[3];
    const float* W2 = (const float*)d_in[4];
    const float* b2 = (const float*)d_in[5];
    const int N = N_NODES;
    const int E = in_sizes[1] / 2;
    const int* src = ei;
    const int* dst = ei + E;

    float* out_hid  = (float*)d_out;                       // N*128
    float* out_x2   = out_hid + (size_t)N * HID;           // N*40
    float* out_logp = out_x2 + (size_t)N * C_OUT;          // N*40

    char* p = (char*)d_ws;
    auto alloc = [&](size_t bytes) { void* r = (void*)p; p += (bytes + 255) & ~255ull; return r; };
    int*   binCount   = (int*)alloc((size_t)(BINS + 1) * 4);   // +1: doneCnt
    int*   bucketBase = (int*)alloc((size_t)(BINS + 1) * 4);
    int*   binCursor  = (int*)alloc((size_t)BINS * 4);
    int*   offsets    = (int*)alloc((size_t)(N + 1) * 4);
    float* dinv       = (float*)alloc((size_t)N * 4);
    unsigned int*   packed = (unsigned int*)alloc((size_t)E * 4);
    unsigned short* col    = (unsigned short*)alloc((size_t)E * 2);
    unsigned short* y1f    = (unsigned short*)alloc((size_t)N * 64 * 2);        // fp8 pairs
    unsigned short* y2b    = (unsigned short*)alloc((size_t)N * C_OUT * 2);     // bf16
    unsigned short* W1bT   = (unsigned short*)alloc((size_t)HID * F_IN * 2);    // bf16 [N][K]
    int* doneCnt = binCount + BINS;

    hipMemsetAsync(binCount, 0, (size_t)(BINS + 1) * 4, stream);
    k_hist<<<512, 256, 0, stream>>>(dst, E, binCount, doneCnt, W1, W1bT,
                                    bucketBase, binCursor, offsets);
    k_partition<<<(E + PCHUNK - 1) / PCHUNK, PTHREADS, 0, stream>>>(src, dst, E, binCursor, packed);
    k_bucket_csr<<<BINS, 256, 0, stream>>>(packed, bucketBase, offsets, dinv, col, N);
    k_gemm1<<<(N + 63) / 64, 256, 0, stream>>>(x, W1bT, dinv, y1f, N);
    k_agg1<<<(N + 3) / 4, 256, 0, stream>>>((const uint2*)y1f, col, offsets, dinv, b1, out_hid, N);
    k_gemm2<<<(N + 127) / 128, 256, 0, stream>>>(out_hid, W2, dinv, y2b, N);
    k_agg2<<<(N + 3) / 4, 256, 0, stream>>>((const uint2*)y2b, col, offsets, dinv, b2, out_x2, out_logp, N);
}

// Round 8
// 265.486 us; speedup vs baseline: 1.0866x; 1.0866x over previous
//
#include <hip/hip_runtime.h>
#include <math.h>

#define N_NODES 50000
#define F_IN 256
#define HID 128
#define C_OUT 40
#define BINS ((N_NODES + 255) / 256)   // 196 buckets of 256 nodes

typedef __attribute__((ext_vector_type(8))) short short8;
typedef __attribute__((ext_vector_type(4))) float floatx4;
typedef __attribute__((ext_vector_type(2))) float floatx2;

__device__ __forceinline__ unsigned short f2bf(float f) {
    unsigned int u = __float_as_uint(f);
    unsigned int r = (u + 0x7FFFu + ((u >> 16) & 1u)) >> 16;
    return (unsigned short)r;
}
__device__ __forceinline__ unsigned int pack2bf(float a, float b) {
    return (unsigned int)f2bf(a) | ((unsigned int)f2bf(b) << 16);
}
__device__ __forceinline__ float bf_lo(unsigned int u) { return __uint_as_float(u << 16); }
__device__ __forceinline__ float bf_hi(unsigned int u) { return __uint_as_float(u & 0xFFFF0000u); }

// ---------------- phase 1: bucket histogram ----------------
__global__ void k_hist(const int* __restrict__ dst, int E, int* __restrict__ binCount) {
    __shared__ int h[BINS];
    for (int i = threadIdx.x; i < BINS; i += 256) h[i] = 0;
    __syncthreads();
    for (int e = blockIdx.x * 256 + threadIdx.x; e < E; e += gridDim.x * 256)
        atomicAdd(&h[dst[e] >> 8], 1);
    __syncthreads();
    for (int i = threadIdx.x; i < BINS; i += 256)
        if (h[i]) atomicAdd(&binCount[i], h[i]);
}

// ---------------- phase 2: scan buckets ----------------
__global__ void k_scan_bins(const int* __restrict__ binCount, int* __restrict__ bucketBase,
                            int* __restrict__ binCursor, int* __restrict__ offsets, int E) {
    __shared__ int sd[256];
    int t = threadIdx.x;
    int v = (t < BINS) ? binCount[t] : 0;
    sd[t] = v; __syncthreads();
    for (int off = 1; off < 256; off <<= 1) {
        int tmp = (t >= off) ? sd[t - off] : 0;
        __syncthreads();
        sd[t] += tmp;
        __syncthreads();
    }
    int ex = sd[t] - v;
    if (t < BINS) { bucketBase[t] = ex; binCursor[t] = ex; }
    if (t == 0) { bucketBase[BINS] = E; offsets[N_NODES] = E; }
}

// ---------------- phase 3: partition edges into buckets ----------------
#define PCHUNK 4096
#define PTHREADS 256
__launch_bounds__(PTHREADS)
__global__ void k_partition(const int* __restrict__ src, const int* __restrict__ dst, int E,
                            int* __restrict__ binCursor, unsigned int* __restrict__ packed) {
    __shared__ unsigned int lpack[PCHUNK];   // (local_dst<<16)|src
    __shared__ unsigned int lpos[PCHUNK];    // (rank<<8)|bin
    __shared__ int lcnt[BINS];
    __shared__ int lrun[BINS];
    int t = threadIdx.x;
    int base = blockIdx.x * PCHUNK;
    int n = E - base; if (n > PCHUNK) n = PCHUNK;
    for (int i = t; i < BINS; i += PTHREADS) lcnt[i] = 0;
    __syncthreads();
    for (int i = t; i < n; i += PTHREADS) {
        int d = dst[base + i], s = src[base + i];
        int bin = d >> 8;
        unsigned int r = (unsigned int)atomicAdd(&lcnt[bin], 1);
        lpack[i] = ((unsigned int)(d & 255) << 16) | (unsigned int)s;
        lpos[i] = (r << 8) | (unsigned int)bin;
    }
    __syncthreads();
    if (t < BINS && lcnt[t] > 0) lrun[t] = atomicAdd(&binCursor[t], lcnt[t]);
    __syncthreads();
    for (int i = t; i < n; i += PTHREADS) {
        unsigned int p = lpos[i];
        int bin = p & 255;
        unsigned int r = p >> 8;
        packed[(size_t)lrun[bin] + r] = lpack[i];
    }
}

// ---------------- phase 4: per-bucket CSR (offsets, dinv, col) ----------------
__launch_bounds__(256)
__global__ void k_bucket_csr(const unsigned int* __restrict__ packed, const int* __restrict__ bucketBase,
                             int* __restrict__ offsets, float* __restrict__ dinv,
                             unsigned short* __restrict__ col, int N) {
    __shared__ int lcnt[256];
    __shared__ int lscan[256];
    __shared__ int lofs[256];
    int b = blockIdx.x, t = threadIdx.x;
    int s = bucketBase[b], e = bucketBase[b + 1];
    lcnt[t] = 0;
    __syncthreads();
    for (int i = s + t; i < e; i += 256) atomicAdd(&lcnt[packed[i] >> 16], 1);
    __syncthreads();
    int v = lcnt[t];
    lscan[t] = v;
    __syncthreads();
    for (int off = 1; off < 256; off <<= 1) {
        int tmp = (t >= off) ? lscan[t - off] : 0;
        __syncthreads();
        lscan[t] += tmp;
        __syncthreads();
    }
    int ex = lscan[t] - v;
    int node = b * 256 + t;
    if (node < N) {
        offsets[node] = s + ex;
        dinv[node] = rsqrtf((float)(v + 1));   // deg incl. self-loop
    }
    __syncthreads();
    lofs[t] = ex;
    lcnt[t] = 0;
    __syncthreads();
    for (int i = s + t; i < e; i += 256) {
        unsigned int p = packed[i];
        int ld = (int)(p >> 16);
        int r = atomicAdd(&lcnt[ld], 1);
        col[(size_t)s + lofs[ld] + r] = (unsigned short)(p & 0xFFFFu);
    }
}

// ---------------- cast W1 -> bf16 transposed [HID][F_IN] ----------------
__global__ void k_castW1(const float* __restrict__ W1, unsigned short* __restrict__ W1bT) {
    int i = blockIdx.x * 256 + threadIdx.x;   // i = n*256 + k
    if (i < HID * F_IN) {
        int n = i >> 8, k = i & 255;
        W1bT[i] = f2bf(W1[(size_t)k * HID + n]);
    }
}

// ---------------- GEMM1 (MFMA bf16): y1f = fp8((x @ W1) * dinv[row]) ----------------
__launch_bounds__(256)
__global__ void k_gemm1(const float* __restrict__ A, const unsigned short* __restrict__ BT,
                        const float* __restrict__ dinv, unsigned short* __restrict__ Yf, int M) {
    __shared__ __align__(16) unsigned short As[64][72];    // 64 rows x 64 bf16 (+8 pad)
    __shared__ __align__(16) unsigned short Bs[128][72];   // 128 n-rows x 64 bf16 (+8 pad)
    int t = threadIdx.x;
    int w = t >> 6, lane = t & 63;
    int q = lane >> 4, m = lane & 15;
    int row0 = blockIdx.x * 64;

    floatx4 acc[4][2];
#pragma unroll
    for (int rt = 0; rt < 4; rt++)
#pragma unroll
        for (int ct = 0; ct < 2; ct++) acc[rt][ct] = (floatx4){0.f, 0.f, 0.f, 0.f};

    int ar = t >> 2;
    int ac = (t & 3) * 16;
    int brow = t >> 1;
    int bh = (t & 1) * 32;

    for (int k0 = 0; k0 < F_IN; k0 += 64) {
        {
            int grow = row0 + ar;
            float4 v0, v1, v2, v3;
            if (grow < M) {
                const float* sp = A + (size_t)grow * F_IN + k0 + ac;
                v0 = *(const float4*)(sp);     v1 = *(const float4*)(sp + 4);
                v2 = *(const float4*)(sp + 8); v3 = *(const float4*)(sp + 12);
            } else {
                v0 = v1 = v2 = v3 = make_float4(0.f, 0.f, 0.f, 0.f);
            }
            uint4 u0, u1;
            u0.x = pack2bf(v0.x, v0.y); u0.y = pack2bf(v0.z, v0.w);
            u0.z = pack2bf(v1.x, v1.y); u0.w = pack2bf(v1.z, v1.w);
            u1.x = pack2bf(v2.x, v2.y); u1.y = pack2bf(v2.z, v2.w);
            u1.z = pack2bf(v3.x, v3.y); u1.w = pack2bf(v3.z, v3.w);
            *(uint4*)&As[ar][ac] = u0;
            *(uint4*)&As[ar][ac + 8] = u1;
        }
        {
            const unsigned short* sp = BT + (size_t)brow * F_IN + k0 + bh;
            uint4 b0 = *(const uint4*)(sp);
            uint4 b1 = *(const uint4*)(sp + 8);
            uint4 b2 = *(const uint4*)(sp + 16);
            uint4 b3 = *(const uint4*)(sp + 24);
            *(uint4*)&Bs[brow][bh] = b0;
            *(uint4*)&Bs[brow][bh + 8] = b1;
            *(uint4*)&Bs[brow][bh + 16] = b2;
            *(uint4*)&Bs[brow][bh + 24] = b3;
        }
        __syncthreads();
#pragma unroll
        for (int kc = 0; kc < 64; kc += 32) {
            short8 af[4];
#pragma unroll
            for (int rt = 0; rt < 4; rt++)
                af[rt] = *(const short8*)&As[rt * 16 + m][kc + q * 8];
#pragma unroll
            for (int ct = 0; ct < 2; ct++) {
                short8 bfr = *(const short8*)&Bs[w * 32 + ct * 16 + m][kc + q * 8];
#pragma unroll
                for (int rt = 0; rt < 4; rt++)
                    acc[rt][ct] = __builtin_amdgcn_mfma_f32_16x16x32_bf16(af[rt], bfr, acc[rt][ct], 0, 0, 0);
            }
        }
        __syncthreads();
    }
#pragma unroll
    for (int rt = 0; rt < 4; rt++) {
#pragma unroll
        for (int r = 0; r < 4; r++) {
            int grow = row0 + rt * 16 + q * 4 + r;
            if (grow < M) {
                float d = dinv[grow];
                int pk = __builtin_amdgcn_cvt_pk_fp8_f32(acc[rt][0][r] * d, acc[rt][1][r] * d, 0, false);
                Yf[(size_t)grow * 64 + w * 16 + m] = (unsigned short)pk;
            }
        }
    }
}

// ---------------- GEMM2: y2b = bf16((hid @ W2) * dinv[row]) ----------------
__launch_bounds__(256)
__global__ void k_gemm2(const float* __restrict__ A, const float* __restrict__ B,
                        const float* __restrict__ dinv, unsigned short* __restrict__ Yb, int M) {
    const int BM = 128, BK = 32, TM = 4, TN = 5;
    __shared__ float As[BM][BK + 4];
    __shared__ float Bs[BK][C_OUT];
    int t = threadIdx.x;
    int tx = t & 7;
    int ty = t >> 3;
    int row0 = blockIdx.x * BM;
    float acc[TM][TN];
#pragma unroll
    for (int i = 0; i < TM; i++)
#pragma unroll
        for (int j = 0; j < TN; j++) acc[i][j] = 0.f;

    int am = t >> 1;

    for (int k0 = 0; k0 < HID; k0 += BK) {
#pragma unroll
        for (int h = 0; h < 4; h++) {
            int kq = (t & 1) + h * 2;
            int row = row0 + am;
            float4 v = (row < M) ? *(const float4*)(A + (size_t)row * HID + k0 + kq * 4)
                                 : make_float4(0.f, 0.f, 0.f, 0.f);
            As[am][kq * 4 + 0] = v.x; As[am][kq * 4 + 1] = v.y;
            As[am][kq * 4 + 2] = v.z; As[am][kq * 4 + 3] = v.w;
        }
        for (int l = t; l < BK * (C_OUT / 4); l += 256) {
            int kk = l / (C_OUT / 4), qq = l % (C_OUT / 4);
            *(float4*)&Bs[kk][qq * 4] = *(const float4*)(B + (size_t)(k0 + kk) * C_OUT + qq * 4);
        }
        __syncthreads();
#pragma unroll
        for (int kk = 0; kk < BK; kk++) {
            float a[TM], bv[TN];
#pragma unroll
            for (int i = 0; i < TM; i++) a[i] = As[ty * TM + i][kk];
#pragma unroll
            for (int j = 0; j < TN; j++) bv[j] = Bs[kk][tx * TN + j];
#pragma unroll
            for (int i = 0; i < TM; i++)
#pragma unroll
                for (int j = 0; j < TN; j++) acc[i][j] = fmaf(a[i], bv[j], acc[i][j]);
        }
        __syncthreads();
    }
#pragma unroll
    for (int i = 0; i < TM; i++) {
        int row = row0 + ty * TM + i;
        if (row < M) {
            float d = dinv[row];
#pragma unroll
            for (int j = 0; j < TN; j++)
                Yb[(size_t)row * C_OUT + tx * TN + j] = f2bf(acc[i][j] * d);
        }
    }
}

// ---------------- agg1: 8 lanes/edge (uint4 fp8 = 16 features), 8 edges/pass ----------------
// y1f ushort p -> features ((p>>4)*32+(p&15), +16); lane lg covers p = lg*8..lg*8+7,
// i.e. features base..base+7 (lo) and base+16..base+23 (hi), base = (lg>>1)*32 + (lg&1)*8.
__device__ __forceinline__ void fp8acc16(uint4 v, float* accLo, float* accHi) {
    unsigned int uu[4] = {v.x, v.y, v.z, v.w};
#pragma unroll
    for (int qq = 0; qq < 4; qq++) {
        floatx2 dA = __builtin_amdgcn_cvt_pk_f32_fp8(uu[qq], false);  // pair k=2q
        floatx2 dB = __builtin_amdgcn_cvt_pk_f32_fp8(uu[qq], true);   // pair k=2q+1
        accLo[2 * qq]     += dA[0]; accHi[2 * qq]     += dA[1];
        accLo[2 * qq + 1] += dB[0]; accHi[2 * qq + 1] += dB[1];
    }
}

__launch_bounds__(256)
__global__ void k_agg1(const uint4* __restrict__ y1f4, const unsigned short* __restrict__ col,
                       const int* __restrict__ offsets, const float* __restrict__ dinv,
                       const float* __restrict__ b1, float* __restrict__ hid, int N) {
    int lane = threadIdx.x & 63;
    int w = threadIdx.x >> 6;
    int node = blockIdx.x * 4 + w;
    if (node >= N) return;
    int g = lane >> 3;      // edge group 0..7
    int lg = lane & 7;      // 8 lanes x uint4 = 128 B row
    int s = offsets[node], e = offsets[node + 1];

    float accLo[8], accHi[8];
#pragma unroll
    for (int i = 0; i < 8; i++) { accLo[i] = 0.f; accHi[i] = 0.f; }
    if (g == 0) fp8acc16(y1f4[(size_t)node * 8 + lg], accLo, accHi);   // self-loop

    for (int t0 = s; t0 < e; t0 += 64) {
        int cnt = e - t0; if (cnt > 64) cnt = 64;
        int jreg = (lane < cnt) ? (int)col[t0 + lane] : 0;
        int passes = (cnt + 7) >> 3;
        int p = 0;
        for (; p + 2 <= passes; p += 2) {
            int idx0 = p * 8 + g, idx1 = idx0 + 8;
            bool va = idx0 < cnt, vb = idx1 < cnt;
            int j0 = __shfl(jreg, va ? idx0 : 0);
            int j1 = __shfl(jreg, vb ? idx1 : 0);
            uint4 u0, u1;
            if (va) u0 = y1f4[(size_t)j0 * 8 + lg];
            if (vb) u1 = y1f4[(size_t)j1 * 8 + lg];
            if (va) fp8acc16(u0, accLo, accHi);
            if (vb) fp8acc16(u1, accLo, accHi);
        }
        for (; p < passes; p++) {
            int idx = p * 8 + g;
            bool valid = idx < cnt;
            int j = __shfl(jreg, valid ? idx : 0);
            if (valid) fp8acc16(y1f4[(size_t)j * 8 + lg], accLo, accHi);
        }
    }
#pragma unroll
    for (int i = 0; i < 8; i++) {
        accLo[i] += __shfl(accLo[i], lane + 32);
        accHi[i] += __shfl(accHi[i], lane + 32);
    }
#pragma unroll
    for (int i = 0; i < 8; i++) {
        accLo[i] += __shfl(accLo[i], lane + 16);
        accHi[i] += __shfl(accHi[i], lane + 16);
    }
#pragma unroll
    for (int i = 0; i < 8; i++) {
        accLo[i] += __shfl(accLo[i], lane + 8);
        accHi[i] += __shfl(accHi[i], lane + 8);
    }
    if (lane < 8) {
        float d = dinv[node];
        int base = (lg >> 1) * 32 + (lg & 1) * 8;
        float4 bL0 = *(const float4*)(b1 + base);
        float4 bL1 = *(const float4*)(b1 + base + 4);
        float4 bH0 = *(const float4*)(b1 + base + 16);
        float4 bH1 = *(const float4*)(b1 + base + 20);
        float4 oL0, oL1, oH0, oH1;
        oL0.x = fmaxf(fmaf(d, accLo[0], bL0.x), 0.f);
        oL0.y = fmaxf(fmaf(d, accLo[1], bL0.y), 0.f);
        oL0.z = fmaxf(fmaf(d, accLo[2], bL0.z), 0.f);
        oL0.w = fmaxf(fmaf(d, accLo[3], bL0.w), 0.f);
        oL1.x = fmaxf(fmaf(d, accLo[4], bL1.x), 0.f);
        oL1.y = fmaxf(fmaf(d, accLo[5], bL1.y), 0.f);
        oL1.z = fmaxf(fmaf(d, accLo[6], bL1.z), 0.f);
        oL1.w = fmaxf(fmaf(d, accLo[7], bL1.w), 0.f);
        oH0.x = fmaxf(fmaf(d, accHi[0], bH0.x), 0.f);
        oH0.y = fmaxf(fmaf(d, accHi[1], bH0.y), 0.f);
        oH0.z = fmaxf(fmaf(d, accHi[2], bH0.z), 0.f);
        oH0.w = fmaxf(fmaf(d, accHi[3], bH0.w), 0.f);
        oH1.x = fmaxf(fmaf(d, accHi[4], bH1.x), 0.f);
        oH1.y = fmaxf(fmaf(d, accHi[5], bH1.y), 0.f);
        oH1.z = fmaxf(fmaf(d, accHi[6], bH1.z), 0.f);
        oH1.w = fmaxf(fmaf(d, accHi[7], bH1.w), 0.f);
        float* op = hid + (size_t)node * HID + base;
        *(float4*)(op) = oL0;
        *(float4*)(op + 4) = oL1;
        *(float4*)(op + 16) = oH0;
        *(float4*)(op + 20) = oH1;
    }
}

// ---------------- agg2: 10 lanes/edge (uint2), 6 edges/pass + softmax ----------------
__launch_bounds__(256)
__global__ void k_agg2(const uint2* __restrict__ y2b2, const unsigned short* __restrict__ col,
                       const int* __restrict__ offsets, const float* __restrict__ dinv,
                       const float* __restrict__ b2, float* __restrict__ x2out,
                       float* __restrict__ logp, int N) {
    int lane = threadIdx.x & 63;
    int w = threadIdx.x >> 6;
    int node = blockIdx.x * 4 + w;
    if (node >= N) return;
    int g = lane / 10;
    int lg = lane - g * 10;
    bool lact = lane < 60;
    int s = offsets[node], e = offsets[node + 1];

    float a0, a1, a2, a3;
    if (lact && g == 0) {
        uint2 sv = y2b2[(size_t)node * 10 + lg];
        a0 = bf_lo(sv.x); a1 = bf_hi(sv.x); a2 = bf_lo(sv.y); a3 = bf_hi(sv.y);
    } else { a0 = a1 = a2 = a3 = 0.f; }

    for (int t0 = s; t0 < e; t0 += 60) {
        int cnt = e - t0; if (cnt > 60) cnt = 60;
        int jreg = (lane < cnt) ? (int)col[t0 + lane] : 0;
        int passes = (cnt + 5) / 6;
        for (int p = 0; p < passes; p++) {
            int idx = p * 6 + g;
            bool valid = lact && idx < cnt;
            int j = __shfl(jreg, valid ? idx : 0);
            if (valid) {
                uint2 v = y2b2[(size_t)j * 10 + lg];
                a0 += bf_lo(v.x); a1 += bf_hi(v.x);
                a2 += bf_lo(v.y); a3 += bf_hi(v.y);
            }
        }
    }
    a0 += __shfl(a0, lane + 30); a1 += __shfl(a1, lane + 30);
    a2 += __shfl(a2, lane + 30); a3 += __shfl(a3, lane + 30);
    float r0 = a0 + __shfl(a0, lane + 10) + __shfl(a0, lane + 20);
    float r1 = a1 + __shfl(a1, lane + 10) + __shfl(a1, lane + 20);
    float r2 = a2 + __shfl(a2, lane + 10) + __shfl(a2, lane + 20);
    float r3 = a3 + __shfl(a3, lane + 10) + __shfl(a3, lane + 20);

    float x0, x1, x2v, x3;
    if (lane < 10) {
        float d = dinv[node];
        float4 bb = ((const float4*)b2)[lg];
        x0 = fmaf(d, r0, bb.x); x1 = fmaf(d, r1, bb.y);
        x2v = fmaf(d, r2, bb.z); x3 = fmaf(d, r3, bb.w);
        float4* xo = (float4*)(x2out + (size_t)node * C_OUT);
        xo[lg] = make_float4(x0, x1, x2v, x3);
    } else { x0 = x1 = x2v = x3 = -INFINITY; }

    float m = fmaxf(fmaxf(x0, x1), fmaxf(x2v, x3));
#pragma unroll
    for (int off = 1; off < 16; off <<= 1) m = fmaxf(m, __shfl_xor(m, off));
    float sum = (lane < 10) ? (expf(x0 - m) + expf(x1 - m) + expf(x2v - m) + expf(x3 - m)) : 0.f;
#pragma unroll
    for (int off = 1; off < 16; off <<= 1) sum += __shfl_xor(sum, off);
    if (lane < 10) {
        float lse = m + logf(sum);
        float4* lo = (float4*)(logp + (size_t)node * C_OUT);
        lo[lg] = make_float4(x0 - lse, x1 - lse, x2v - lse, x3 - lse);
    }
}

// ---------------- launcher ----------------
extern "C" void kernel_launch(void* const* d_in, const int* in_sizes, int n_in,
                              void* d_out, int out_size, void* d_ws, size_t ws_size,
                              hipStream_t stream) {
    const float* x  = (const float*)d_in[0];
    const int*   ei = (const int*)d_in[1];
    const float* W1 = (const float*)d_in[2];
    const float* b1 = (const float*)d_in[3];
    const float* W2 = (const float*)d_in[4];
    const float* b2 = (const float*)d_in[5];
    const int N = N_NODES;
    const int E = in_sizes[1] / 2;
    const int* src = ei;
    const int* dst = ei + E;

    float* out_hid  = (float*)d_out;                       // N*128
    float* out_x2   = out_hid + (size_t)N * HID;           // N*40
    float* out_logp = out_x2 + (size_t)N * C_OUT;          // N*40

    char* p = (char*)d_ws;
    auto alloc = [&](size_t bytes) { void* r = (void*)p; p += (bytes + 255) & ~255ull; return r; };
    int*   binCount   = (int*)alloc((size_t)BINS * 4);
    int*   bucketBase = (int*)alloc((size_t)(BINS + 1) * 4);
    int*   binCursor  = (int*)alloc((size_t)BINS * 4);
    int*   offsets    = (int*)alloc((size_t)(N + 1) * 4);
    float* dinv       = (float*)alloc((size_t)N * 4);
    unsigned int*   packed = (unsigned int*)alloc((size_t)E * 4);
    unsigned short* col    = (unsigned short*)alloc((size_t)E * 2);
    unsigned short* y1f    = (unsigned short*)alloc((size_t)N * 64 * 2);        // fp8 pairs
    unsigned short* y2b    = (unsigned short*)alloc((size_t)N * C_OUT * 2);     // bf16
    unsigned short* W1bT   = (unsigned short*)alloc((size_t)HID * F_IN * 2);    // bf16 [N][K]

    hipMemsetAsync(binCount, 0, (size_t)BINS * 4, stream);
    k_hist<<<512, 256, 0, stream>>>(dst, E, binCount);
    k_scan_bins<<<1, 256, 0, stream>>>(binCount, bucketBase, binCursor, offsets, E);
    k_partition<<<(E + PCHUNK - 1) / PCHUNK, PTHREADS, 0, stream>>>(src, dst, E, binCursor, packed);
    k_bucket_csr<<<BINS, 256, 0, stream>>>(packed, bucketBase, offsets, dinv, col, N);
    k_castW1<<<(HID * F_IN + 255) / 256, 256, 0, stream>>>(W1, W1bT);
    k_gemm1<<<(N + 63) / 64, 256, 0, stream>>>(x, W1bT, dinv, y1f, N);
    k_agg1<<<(N + 3) / 4, 256, 0, stream>>>((const uint4*)y1f, col, offsets, dinv, b1, out_hid, N);
    k_gemm2<<<(N + 127) / 128, 256, 0, stream>>>(out_hid, W2, dinv, y2b, N);
    k_agg2<<<(N + 3) / 4, 256, 0, stream>>>((const uint2*)y2b, col, offsets, dinv, b2, out_x2, out_logp, N);
}